// Round 2
// baseline (1789.472 us; speedup 1.0000x reference)
//
#include <hip/hip_runtime.h>

// LapCluster fused fp32 pipeline for MI355X — round 2.
// Key changes vs round 1:
//  - poolc tables computed ONCE per batch in tiny pool_reduce kernels
//    (was: recomputed per block with a 16-way-bank-conflict LDS pattern).
//  - pool partials laid out [feature][cluster] (k*16+cl) so LDS atomics
//    spread across 16 banks instead of all hitting one.
//  - 4 barriers/tile (was 6-7) via double-buffered f3 chunk LDS.
// Clusters always in [0,16) (randint high = min(NUM_CLUSTER)).
// Pool trick: W*[f3,pool] = W[:, :128]*f3 + poolc[o][cluster] (precomputed).
// ReLU outputs >= 0 -> float-bits unsigned atomicMax exact, 0-init valid.

#define TPB 512          // 8 waves
#define PT 64            // points per tile == wave size
#define NPB 16384        // N per batch
#define NPTS 131072      // B*N
#define NC 16
#define NBLK 512         // 64 blocks/batch, 4 tiles each

__device__ __forceinline__ float relu_(float v) { return fmaxf(v, 0.f); }

// acc[j] += sum_k W[(row0+j)*STRIDE + k] * Ain[k][lane]; W rows wave-uniform -> s_loads.
template<int K, int CPT, int STRIDE>
__device__ __forceinline__ void accum_lds(float* acc, const float* Ain,
                                          const float* __restrict__ Wrow0, int lane) {
#pragma unroll 2
  for (int k0 = 0; k0 < K; k0 += 8) {
    float a[8];
#pragma unroll
    for (int kk = 0; kk < 8; ++kk) a[kk] = Ain[(k0 + kk) * PT + lane];
#pragma unroll
    for (int j = 0; j < CPT; ++j) {
#pragma unroll
      for (int kk = 0; kk < 8; ++kk)
        acc[j] = fmaf(Wrow0[j * STRIDE + k0 + kk], a[kk], acc[j]);
    }
  }
}

// ---- per-batch pool table: pf = max over 64 block-partials; poolc[o][cl] = bias + W[:,128:]*pf
template<int O>
__global__ void __launch_bounds__(1024) pool_reduce_kern(
    const float* __restrict__ part, const float* __restrict__ W,
    const float* __restrict__ bias, float* __restrict__ poolc_g) {
  __shared__ float pfL[2048];        // [k][cl] = k*16+cl
  __shared__ float Wl[O * 129];      // padded: row stride 129
  const int tid = threadIdx.x;
  const int b = blockIdx.x;
  for (int i = tid; i < 2048; i += 1024) {
    float m = 0.f;
    const float* pp = part + (size_t)(b * 64) * 2048 + i;
    for (int blk = 0; blk < 64; ++blk) m = fmaxf(m, pp[(size_t)blk * 2048]);
    pfL[i] = m;
  }
  for (int i = tid; i < O * 128; i += 1024) {
    const int o = i >> 7, k = i & 127;
    Wl[o * 129 + k] = W[o * 256 + 128 + k];
  }
  __syncthreads();
  constexpr int SH = (O == 64) ? 6 : 7;
  for (int e = tid; e < O * 16; e += 1024) {
    const int o = e & (O - 1);        // lane-varying -> Wl 2-way (free)
    const int cl = e >> SH;           // wave-uniform -> pfL broadcast (free)
    float s = bias[o];
    const float* wr = &Wl[o * 129];
    const float* pr = &pfL[cl];
#pragma unroll 4
    for (int k = 0; k < 128; ++k) s = fmaf(wr[k], pr[k * 16], s);
    poolc_g[(size_t)b * (O * 16) + o * 16 + cl] = s;
  }
}

// ---- Stage 0: x -> f256 -> f64 -> f128 (global) + partial pool(clusters[0])
__global__ void __launch_bounds__(TPB) k0_kern(
    const float* __restrict__ x, const int* __restrict__ cls,
    const float* __restrict__ w_in, const float* __restrict__ b_in,
    const float* __restrict__ w1, const float* __restrict__ b1,
    const float* __restrict__ w2, const float* __restrict__ b2,
    float* __restrict__ f128g, float* __restrict__ part0) {
  __shared__ float A0[128 * PT];     // f256 ch 0..127; rows 0..63 reused as A64
  __shared__ float A1[128 * PT];     // f256 ch 128..255
  __shared__ unsigned pool_s[128 * NC];   // [k][cl]
  const int tid = threadIdx.x;
  const int lane = tid & 63;
  const int g = __builtin_amdgcn_readfirstlane(tid >> 6);
  const int b = blockIdx.x >> 6;
  for (int i = tid; i < 128 * NC; i += TPB) pool_s[i] = 0u;
  __syncthreads();

  for (int t = 0; t < 4; ++t) {
    const int pg = (blockIdx.x * 4 + t) * PT + lane;
    const int n = pg & (NPB - 1);
    float xr[28];
    {
      const float4* xp = reinterpret_cast<const float4*>(x + (size_t)pg * 28);
#pragma unroll
      for (int q = 0; q < 7; ++q) {
        float4 v = xp[q];
        xr[4 * q] = v.x; xr[4 * q + 1] = v.y; xr[4 * q + 2] = v.z; xr[4 * q + 3] = v.w;
      }
    }
    // f256 both chunks (no barrier between: disjoint per-wave rows)
#pragma unroll
    for (int c = 0; c < 2; ++c) {
      const int o0 = c * 128 + g * 16;
      float acc[16];
#pragma unroll
      for (int j = 0; j < 16; ++j) acc[j] = b_in[o0 + j];
#pragma unroll
      for (int k = 0; k < 28; ++k) {
#pragma unroll
        for (int j = 0; j < 16; ++j)
          acc[j] = fmaf(w_in[(o0 + j) * 28 + k], xr[k], acc[j]);
      }
      float* dst = c ? A1 : A0;
#pragma unroll
      for (int j = 0; j < 16; ++j) dst[(g * 16 + j) * PT + lane] = relu_(acc[j]);
    }
    __syncthreads();   // B1
    float acc64[8];
#pragma unroll
    for (int j = 0; j < 8; ++j) acc64[j] = b1[g * 8 + j];
    accum_lds<128, 8, 256>(acc64, A0, w1 + (g * 8) * 256, lane);
    accum_lds<128, 8, 256>(acc64, A1, w1 + (g * 8) * 256 + 128, lane);
    __syncthreads();   // B2: all waves done reading A0 before A64 overwrite
#pragma unroll
    for (int j = 0; j < 8; ++j) A0[(g * 8 + j) * PT + lane] = relu_(acc64[j]);
    __syncthreads();   // B3
    {
      const int o0 = g * 16;
      float acc[16];
#pragma unroll
      for (int j = 0; j < 16; ++j) acc[j] = b2[o0 + j];
      accum_lds<64, 16, 64>(acc, A0, w2 + o0 * 64, lane);
      const int cl = cls[pg];
#pragma unroll
      for (int j = 0; j < 16; ++j) {
        float v = relu_(acc[j]);
        f128g[(size_t)(b * 128 + o0 + j) * NPB + n] = v;
        atomicMax(&pool_s[(o0 + j) * NC + cl], __float_as_uint(v));
      }
    }
    __syncthreads();   // B4: end of tile
  }
  for (int i = tid; i < 128 * NC; i += TPB)
    part0[(size_t)blockIdx.x * 2048 + i] = __uint_as_float(pool_s[i]);
}

// ---- Stages 1,2: f128 -> f3 ; f64 = w1*[f3,pool] ; f128' = w2 ; partial pool
__global__ void __launch_bounds__(TPB) kmid_kern(
    float* __restrict__ f128g,
    const float* __restrict__ poolc_g, float* __restrict__ part_cur,
    const int* __restrict__ cls,
    const float* __restrict__ w3, const float* __restrict__ b3,
    const float* __restrict__ w1, const float* __restrict__ b1,
    const float* __restrict__ w2, const float* __restrict__ b2,
    int S) {
  __shared__ float A128s[128 * PT];  // f128 tile; rows 0..63 reused as A64
  __shared__ float F3a[64 * PT];
  __shared__ float F3b[64 * PT];
  __shared__ float poolcL[64 * NC];  // [o][cl]
  __shared__ unsigned pool_s[128 * NC];
  const int tid = threadIdx.x;
  const int lane = tid & 63;
  const int g = __builtin_amdgcn_readfirstlane(tid >> 6);
  const int b = blockIdx.x >> 6;
  const float* w3s = w3 + (size_t)(S - 1) * 128 * 128;
  const float* b3s = b3 + (S - 1) * 128;
  const float* w1s = w1 + (size_t)S * 64 * 256;
  const float* w2s = w2 + (size_t)S * 128 * 64;
  const float* b2s = b2 + S * 128;
  const int* clg = cls + (size_t)(S - 1) * NPTS;
  const int* clp = cls + (size_t)S * NPTS;
  for (int i = tid; i < 128 * NC; i += TPB) pool_s[i] = 0u;
  for (int i = tid; i < 64 * NC; i += TPB) poolcL[i] = poolc_g[(size_t)b * 1024 + i];
  __syncthreads();

  for (int t = 0; t < 4; ++t) {
    const int pg0 = (blockIdx.x * 4 + t) * PT;
    const int n0 = pg0 & (NPB - 1);
    {
      const float4* src = reinterpret_cast<const float4*>(f128g + (size_t)b * 128 * NPB + n0);
      float4* dst = reinterpret_cast<float4*>(A128s);
      for (int i4 = tid; i4 < 128 * (PT / 4); i4 += TPB) {
        const int r = i4 >> 4, q = i4 & 15;
        dst[i4] = src[(size_t)r * (NPB / 4) + q];
      }
    }
    const int cg = clg[pg0 + lane];
    const int cp = clp[pg0 + lane];
    __syncthreads();   // B1
    // f3 both chunks into separate buffers
#pragma unroll
    for (int c = 0; c < 2; ++c) {
      const int oc = c * 64 + g * 8;
      float acc[8];
#pragma unroll
      for (int j = 0; j < 8; ++j) acc[j] = b3s[oc + j];
      accum_lds<128, 8, 128>(acc, A128s, w3s + oc * 128, lane);
      float* dst = c ? F3b : F3a;
#pragma unroll
      for (int j = 0; j < 8; ++j) dst[(g * 8 + j) * PT + lane] = relu_(acc[j]);
    }
    __syncthreads();   // B2: f3 done; A128s dead
    float acc64[8];
#pragma unroll
    for (int j = 0; j < 8; ++j) acc64[j] = poolcL[(g * 8 + j) * NC + cg];
    accum_lds<64, 8, 256>(acc64, F3a, w1s + (g * 8) * 256, lane);
    accum_lds<64, 8, 256>(acc64, F3b, w1s + (g * 8) * 256 + 64, lane);
    // A64 into A128s rows g*8.. (readers finished at B2)
#pragma unroll
    for (int j = 0; j < 8; ++j) A128s[(g * 8 + j) * PT + lane] = relu_(acc64[j]);
    __syncthreads();   // B3
    {
      const int o0 = g * 16;
      float acc[16];
#pragma unroll
      for (int j = 0; j < 16; ++j) acc[j] = b2s[o0 + j];
      accum_lds<64, 16, 64>(acc, A128s, w2s + o0 * 64, lane);
#pragma unroll
      for (int j = 0; j < 16; ++j) {
        float v = relu_(acc[j]);
        f128g[(size_t)(b * 128 + o0 + j) * NPB + n0 + lane] = v;
        atomicMax(&pool_s[(o0 + j) * NC + cp], __float_as_uint(v));
      }
    }
    __syncthreads();   // B4
  }
  for (int i = tid; i < 128 * NC; i += TPB)
    part_cur[(size_t)blockIdx.x * 2048 + i] = __uint_as_float(pool_s[i]);
}

// ---- Head: f128 -> f3 ; o1 = wo1*[f3,pool2] ; o2 = wo2*o1 ; global max
__global__ void __launch_bounds__(TPB) k3_kern(
    const float* __restrict__ f128g, const float* __restrict__ poolco_g,
    const int* __restrict__ cls,
    const float* __restrict__ w3, const float* __restrict__ b3,
    const float* __restrict__ wo1,
    const float* __restrict__ wo2, const float* __restrict__ bo2,
    float* __restrict__ out) {
  __shared__ float A128s[128 * PT];  // f128 tile; then O1
  __shared__ float F3a[64 * PT];
  __shared__ float F3b[64 * PT];
  __shared__ float poolcoL[128 * NC];
  const int tid = threadIdx.x;
  const int lane = tid & 63;
  const int g = __builtin_amdgcn_readfirstlane(tid >> 6);
  const int b = blockIdx.x >> 6;
  const float* w3s = w3 + (size_t)2 * 128 * 128;
  const float* b3s = b3 + 2 * 128;
  const int* clg = cls + (size_t)2 * NPTS;
  for (int i = tid; i < 128 * NC; i += TPB) poolcoL[i] = poolco_g[(size_t)b * 2048 + i];
  __syncthreads();
  const int o0 = g * 16;
  float omax[16];
#pragma unroll
  for (int j = 0; j < 16; ++j) omax[j] = 0.f;

  for (int t = 0; t < 4; ++t) {
    const int pg0 = (blockIdx.x * 4 + t) * PT;
    const int n0 = pg0 & (NPB - 1);
    {
      const float4* src = reinterpret_cast<const float4*>(f128g + (size_t)b * 128 * NPB + n0);
      float4* dst = reinterpret_cast<float4*>(A128s);
      for (int i4 = tid; i4 < 128 * (PT / 4); i4 += TPB) {
        const int r = i4 >> 4, q = i4 & 15;
        dst[i4] = src[(size_t)r * (NPB / 4) + q];
      }
    }
    const int cl = clg[pg0 + lane];
    __syncthreads();   // B1
#pragma unroll
    for (int c = 0; c < 2; ++c) {
      const int oc = c * 64 + g * 8;
      float acc[8];
#pragma unroll
      for (int j = 0; j < 8; ++j) acc[j] = b3s[oc + j];
      accum_lds<128, 8, 128>(acc, A128s, w3s + oc * 128, lane);
      float* dst = c ? F3b : F3a;
#pragma unroll
      for (int j = 0; j < 8; ++j) dst[(g * 8 + j) * PT + lane] = relu_(acc[j]);
    }
    __syncthreads();   // B2
    float acco1[16];
#pragma unroll
    for (int j = 0; j < 16; ++j) acco1[j] = poolcoL[(o0 + j) * NC + cl];
    accum_lds<64, 16, 256>(acco1, F3a, wo1 + o0 * 256, lane);
    accum_lds<64, 16, 256>(acco1, F3b, wo1 + o0 * 256 + 64, lane);
#pragma unroll
    for (int j = 0; j < 16; ++j) A128s[(o0 + j) * PT + lane] = relu_(acco1[j]);  // O1
    __syncthreads();   // B3
    {
      float acc[16];
#pragma unroll
      for (int j = 0; j < 16; ++j) acc[j] = bo2[o0 + j];
      accum_lds<128, 16, 128>(acc, A128s, wo2 + o0 * 128, lane);
#pragma unroll
      for (int j = 0; j < 16; ++j) omax[j] = fmaxf(omax[j], relu_(acc[j]));
    }
    __syncthreads();   // B4
  }
#pragma unroll
  for (int j = 0; j < 16; ++j) {
    float m = omax[j];
#pragma unroll
    for (int off = 32; off; off >>= 1) m = fmaxf(m, __shfl_xor(m, off));
    if (lane == 0)
      atomicMax(reinterpret_cast<unsigned*>(&out[b * 128 + o0 + j]), __float_as_uint(m));
  }
}

extern "C" void kernel_launch(void* const* d_in, const int* in_sizes, int n_in,
                              void* d_out, int out_size, void* d_ws, size_t ws_size,
                              hipStream_t stream) {
  const float* x    = (const float*)d_in[0];
  const int*   cls  = (const int*)d_in[1];
  const float* w_in = (const float*)d_in[2];
  const float* b_in = (const float*)d_in[3];
  const float* w1   = (const float*)d_in[4];
  const float* b1   = (const float*)d_in[5];
  const float* w2   = (const float*)d_in[6];
  const float* b2   = (const float*)d_in[7];
  const float* w3   = (const float*)d_in[8];
  const float* b3   = (const float*)d_in[9];
  const float* wo1  = (const float*)d_in[10];
  const float* bo1  = (const float*)d_in[11];
  const float* wo2  = (const float*)d_in[12];
  const float* bo2  = (const float*)d_in[13];
  float* out = (float*)d_out;

  char* ws = (char*)d_ws;
  float* f128g = (float*)ws;                           // 64 MB
  float* part0 = (float*)(ws + ((size_t)64 << 20));    // 3 x 4 MB
  float* part1 = part0 + (size_t)NBLK * 2048;
  float* part2 = part1 + (size_t)NBLK * 2048;
  float* poolc1 = part2 + (size_t)NBLK * 2048;         // 8*1024
  float* poolc2 = poolc1 + 8 * 1024;
  float* poolco = poolc2 + 8 * 1024;                   // 8*2048

  hipMemsetAsync(d_out, 0, 1024 * sizeof(float), stream);

  k0_kern<<<NBLK, TPB, 0, stream>>>(x, cls, w_in, b_in, w1, b1, w2, b2, f128g, part0);
  pool_reduce_kern<64><<<8, 1024, 0, stream>>>(part0, w1 + (size_t)1 * 64 * 256, b1 + 64, poolc1);
  kmid_kern<<<NBLK, TPB, 0, stream>>>(f128g, poolc1, part1, cls, w3, b3, w1, b1, w2, b2, 1);
  pool_reduce_kern<64><<<8, 1024, 0, stream>>>(part1, w1 + (size_t)2 * 64 * 256, b1 + 2 * 64, poolc2);
  kmid_kern<<<NBLK, TPB, 0, stream>>>(f128g, poolc2, part2, cls, w3, b3, w1, b1, w2, b2, 2);
  pool_reduce_kern<128><<<8, 1024, 0, stream>>>(part2, wo1, bo1, poolco);
  k3_kern<<<NBLK, TPB, 0, stream>>>(f128g, poolco, cls, w3, b3, wo1, wo2, bo2, out);
}

// Round 3
// 1362.594 us; speedup vs baseline: 1.3133x; 1.3133x over previous
//
#include <hip/hip_runtime.h>

// LapCluster fused fp32 pipeline for MI355X — round 3.
// Post-mortem r2: 72-76 KB LDS/block -> 1 block/CU -> latency-bound (VALUBusy 50%,
// occupancy 24%). Fix: kernel boundary moved from f128 to f3 so each stage kernel
// flows through ONE 32 KB LDS buffer (stage tile -> A64 -> f128 -> w3), LDS <= 44 KB,
// grid 1024, launch_bounds for 3-4 blocks/CU. Pool partials via global float-bit
// atomicMax into per-batch [2048] tables (ReLU >= 0 so 0-init valid, bits ordered).
// Pool trick: W*[f3,pool] = W[:, :128]*f3 + poolc[o][cluster] (per-batch tables).

#define TPB 512          // 8 waves
#define PT 64            // points per tile == wave size
#define NPB 16384        // N per batch
#define NPTS 131072      // B*N
#define NC 16
#define TILES 2
#define NBLK 1024        // 128 blocks/batch

__device__ __forceinline__ float relu_(float v) { return fmaxf(v, 0.f); }

// acc[j] += sum_k W[(row0+j)*STRIDE + k] * Ain[k][lane]; W rows wave-uniform -> s_loads.
template<int K, int CPT, int STRIDE>
__device__ __forceinline__ void accum_lds(float* acc, const float* Ain,
                                          const float* __restrict__ Wrow0, int lane) {
#pragma unroll 2
  for (int k0 = 0; k0 < K; k0 += 8) {
    float a[8];
#pragma unroll
    for (int kk = 0; kk < 8; ++kk) a[kk] = Ain[(k0 + kk) * PT + lane];
#pragma unroll
    for (int j = 0; j < CPT; ++j) {
#pragma unroll
      for (int kk = 0; kk < 8; ++kk)
        acc[j] = fmaf(Wrow0[j * STRIDE + k0 + kk], a[kk], acc[j]);
    }
  }
}

// ---- per-batch poolc table: poolc[o][cl] = bias[o] + W[o,128:]*pool (pool = maxed table)
template<int O>
__global__ void __launch_bounds__(1024) pool_reduce_kern(
    const unsigned* __restrict__ part, const float* __restrict__ W,
    const float* __restrict__ bias, float* __restrict__ poolc_g) {
  __shared__ float pfL[2048];        // [k][cl] = k*16+cl
  __shared__ float Wl[O * 129];      // padded row stride
  const int tid = threadIdx.x;
  const int b = blockIdx.x;
  for (int i = tid; i < 2048; i += 1024) pfL[i] = __uint_as_float(part[b * 2048 + i]);
  for (int i = tid; i < O * 128; i += 1024) {
    const int o = i >> 7, k = i & 127;
    Wl[o * 129 + k] = W[o * 256 + 128 + k];
  }
  __syncthreads();
  constexpr int SH = (O == 64) ? 6 : 7;
  for (int e = tid; e < O * 16; e += 1024) {
    const int o = e & (O - 1);        // lane-varying -> Wl 2-way (free)
    const int cl = e >> SH;           // wave-uniform -> pfL broadcast
    float s = bias[o];
    const float* wr = &Wl[o * 129];
    const float* pr = &pfL[cl];
#pragma unroll 4
    for (int k = 0; k < 128; ++k) s = fmaf(wr[k], pr[k * 16], s);
    poolc_g[(size_t)b * (O * 16) + o * 16 + cl] = s;
  }
}

// ---- Stage 0: x -> f256 -> f64(w1[0]) -> f128(w2[0]) -> pool0 + f3_0(w3[0]) -> global
__global__ void __launch_bounds__(TPB, 6) k0_kern(
    const float* __restrict__ x, const int* __restrict__ cls,
    const float* __restrict__ w_in, const float* __restrict__ b_in,
    const float* __restrict__ w1, const float* __restrict__ b1,
    const float* __restrict__ w2, const float* __restrict__ b2,
    const float* __restrict__ w3, const float* __restrict__ b3,
    float* __restrict__ f3g, unsigned* __restrict__ part0) {
  __shared__ float F[128 * PT];            // f256 chunk -> A64 -> f128
  __shared__ unsigned pool_s[128 * NC];    // [ch][cl]
  const int tid = threadIdx.x;
  const int lane = tid & 63;
  const int g = __builtin_amdgcn_readfirstlane(tid >> 6);
  const int b = blockIdx.x >> 7;
  for (int i = tid; i < 128 * NC; i += TPB) pool_s[i] = 0u;
  __syncthreads();

  for (int t = 0; t < TILES; ++t) {
    const int pg = (blockIdx.x * TILES + t) * PT + lane;
    const int n = pg & (NPB - 1);
    float xr[28];
    {
      const float4* xp = reinterpret_cast<const float4*>(x + (size_t)pg * 28);
#pragma unroll
      for (int q = 0; q < 7; ++q) {
        float4 v = xp[q];
        xr[4 * q] = v.x; xr[4 * q + 1] = v.y; xr[4 * q + 2] = v.z; xr[4 * q + 3] = v.w;
      }
    }
    float acc64[8];
#pragma unroll
    for (int j = 0; j < 8; ++j) acc64[j] = b1[g * 8 + j];
#pragma unroll
    for (int c = 0; c < 2; ++c) {      // f256 in two 128-ch chunks through F
      const int o0 = c * 128 + g * 16;
      float acc[16];
#pragma unroll
      for (int j = 0; j < 16; ++j) acc[j] = b_in[o0 + j];
#pragma unroll
      for (int k = 0; k < 28; ++k) {
#pragma unroll
        for (int j = 0; j < 16; ++j)
          acc[j] = fmaf(w_in[(o0 + j) * 28 + k], xr[k], acc[j]);
      }
#pragma unroll
      for (int j = 0; j < 16; ++j) F[(g * 16 + j) * PT + lane] = relu_(acc[j]);
      __syncthreads();                 // chunk staged
      accum_lds<128, 8, 256>(acc64, F, w1 + (g * 8) * 256 + c * 128, lane);
      __syncthreads();                 // reads done before overwrite
    }
#pragma unroll
    for (int j = 0; j < 8; ++j) F[(g * 8 + j) * PT + lane] = relu_(acc64[j]);  // A64
    __syncthreads();
    const int o0 = g * 16;
    float f128v[16];
#pragma unroll
    for (int j = 0; j < 16; ++j) f128v[j] = b2[o0 + j];
    accum_lds<64, 16, 64>(f128v, F, w2 + o0 * 64, lane);
    const int cl0 = cls[pg];
#pragma unroll
    for (int j = 0; j < 16; ++j) {
      f128v[j] = relu_(f128v[j]);
      atomicMax(&pool_s[(o0 + j) * NC + cl0], __float_as_uint(f128v[j]));
    }
    __syncthreads();                   // A64 reads done
#pragma unroll
    for (int j = 0; j < 16; ++j) F[(o0 + j) * PT + lane] = f128v[j];
    __syncthreads();                   // f128 staged
    float w3a[16];
#pragma unroll
    for (int j = 0; j < 16; ++j) w3a[j] = b3[o0 + j];
    accum_lds<128, 16, 128>(w3a, F, w3 + o0 * 128, lane);
#pragma unroll
    for (int j = 0; j < 16; ++j)
      f3g[(size_t)(b * 128 + o0 + j) * NPB + n] = relu_(w3a[j]);
    __syncthreads();                   // w3 reads done before next tile
  }
  for (int i = tid; i < 128 * NC; i += TPB)
    atomicMax(&part0[(size_t)b * 2048 + i], pool_s[i]);
}

// ---- Stages 1,2: f3_{S-1} -> f64(w1[S]+poolc) -> f128(w2[S]) -> pool_S + f3_S(w3[S])
__global__ void __launch_bounds__(TPB, 8) kmid_kern(
    float* __restrict__ f3g,
    const float* __restrict__ poolc_g, unsigned* __restrict__ part_cur,
    const int* __restrict__ cls,
    const float* __restrict__ w1,
    const float* __restrict__ w2, const float* __restrict__ b2,
    const float* __restrict__ w3, const float* __restrict__ b3,
    int S) {
  __shared__ float F[128 * PT];            // f3 in -> A64 -> f128
  __shared__ float poolcL[64 * NC];
  __shared__ unsigned pool_s[128 * NC];
  const int tid = threadIdx.x;
  const int lane = tid & 63;
  const int g = __builtin_amdgcn_readfirstlane(tid >> 6);
  const int b = blockIdx.x >> 7;
  const float* w1s = w1 + (size_t)S * 64 * 256;
  const float* w2s = w2 + (size_t)S * 128 * 64;
  const float* b2s = b2 + S * 128;
  const float* w3s = w3 + (size_t)S * 128 * 128;
  const float* b3s = b3 + S * 128;
  const int* clg = cls + (size_t)(S - 1) * NPTS;   // for poolc lookup
  const int* clp = cls + (size_t)S * NPTS;          // for pooling
  for (int i = tid; i < 128 * NC; i += TPB) pool_s[i] = 0u;
  for (int i = tid; i < 64 * NC; i += TPB) poolcL[i] = poolc_g[(size_t)b * 1024 + i];
  __syncthreads();

  for (int t = 0; t < TILES; ++t) {
    const int pg0 = (blockIdx.x * TILES + t) * PT;
    const int n0 = pg0 & (NPB - 1);
    {  // stage f3 tile
      const float4* src = reinterpret_cast<const float4*>(f3g + (size_t)b * 128 * NPB + n0);
      float4* dst = reinterpret_cast<float4*>(F);
      for (int i4 = tid; i4 < 128 * (PT / 4); i4 += TPB) {
        const int r = i4 >> 4, q = i4 & 15;
        dst[i4] = src[(size_t)r * (NPB / 4) + q];
      }
    }
    const int cg = clg[pg0 + lane];
    const int cp = clp[pg0 + lane];
    __syncthreads();                   // staged
    float acc64[8];
#pragma unroll
    for (int j = 0; j < 8; ++j) acc64[j] = poolcL[(g * 8 + j) * NC + cg];
    accum_lds<128, 8, 256>(acc64, F, w1s + (g * 8) * 256, lane);
    __syncthreads();                   // w1 reads done
#pragma unroll
    for (int j = 0; j < 8; ++j) F[(g * 8 + j) * PT + lane] = relu_(acc64[j]);  // A64
    __syncthreads();
    const int o0 = g * 16;
    float f128v[16];
#pragma unroll
    for (int j = 0; j < 16; ++j) f128v[j] = b2s[o0 + j];
    accum_lds<64, 16, 64>(f128v, F, w2s + o0 * 64, lane);
#pragma unroll
    for (int j = 0; j < 16; ++j) {
      f128v[j] = relu_(f128v[j]);
      atomicMax(&pool_s[(o0 + j) * NC + cp], __float_as_uint(f128v[j]));
    }
    __syncthreads();                   // A64 reads done
#pragma unroll
    for (int j = 0; j < 16; ++j) F[(o0 + j) * PT + lane] = f128v[j];
    __syncthreads();                   // f128 staged
    float w3a[16];
#pragma unroll
    for (int j = 0; j < 16; ++j) w3a[j] = b3s[o0 + j];
    accum_lds<128, 16, 128>(w3a, F, w3s + o0 * 128, lane);
#pragma unroll
    for (int j = 0; j < 16; ++j)
      f3g[(size_t)(b * 128 + o0 + j) * NPB + n0 + lane] = relu_(w3a[j]);
    __syncthreads();                   // w3 reads done before next tile
  }
  for (int i = tid; i < 128 * NC; i += TPB)
    atomicMax(&part_cur[(size_t)b * 2048 + i], pool_s[i]);
}

// ---- Head: f3_2 -> o1(wo1+poolco) -> o2(wo2) -> global max
__global__ void __launch_bounds__(TPB, 8) k3_kern(
    const float* __restrict__ f3g, const float* __restrict__ poolco_g,
    const int* __restrict__ cls,
    const float* __restrict__ wo1,
    const float* __restrict__ wo2, const float* __restrict__ bo2,
    float* __restrict__ out) {
  __shared__ float F[128 * PT];            // f3 in -> O1
  __shared__ float poolcoL[128 * NC];
  const int tid = threadIdx.x;
  const int lane = tid & 63;
  const int g = __builtin_amdgcn_readfirstlane(tid >> 6);
  const int b = blockIdx.x >> 7;
  const int* clg = cls + (size_t)2 * NPTS;
  for (int i = tid; i < 128 * NC; i += TPB) poolcoL[i] = poolco_g[(size_t)b * 2048 + i];
  __syncthreads();
  const int o0 = g * 16;
  float omax[16];
#pragma unroll
  for (int j = 0; j < 16; ++j) omax[j] = 0.f;

  for (int t = 0; t < TILES; ++t) {
    const int pg0 = (blockIdx.x * TILES + t) * PT;
    const int n0 = pg0 & (NPB - 1);
    {
      const float4* src = reinterpret_cast<const float4*>(f3g + (size_t)b * 128 * NPB + n0);
      float4* dst = reinterpret_cast<float4*>(F);
      for (int i4 = tid; i4 < 128 * (PT / 4); i4 += TPB) {
        const int r = i4 >> 4, q = i4 & 15;
        dst[i4] = src[(size_t)r * (NPB / 4) + q];
      }
    }
    const int cl = clg[pg0 + lane];
    __syncthreads();
    float acco1[16];
#pragma unroll
    for (int j = 0; j < 16; ++j) acco1[j] = poolcoL[(o0 + j) * NC + cl];
    accum_lds<128, 16, 256>(acco1, F, wo1 + o0 * 256, lane);
    __syncthreads();                   // o1 reads done
#pragma unroll
    for (int j = 0; j < 16; ++j) F[(o0 + j) * PT + lane] = relu_(acco1[j]);  // O1
    __syncthreads();
    float acc[16];
#pragma unroll
    for (int j = 0; j < 16; ++j) acc[j] = bo2[o0 + j];
    accum_lds<128, 16, 128>(acc, F, wo2 + o0 * 128, lane);
#pragma unroll
    for (int j = 0; j < 16; ++j) omax[j] = fmaxf(omax[j], relu_(acc[j]));
    __syncthreads();                   // o2 reads done before next tile
  }
#pragma unroll
  for (int j = 0; j < 16; ++j) {
    float m = omax[j];
#pragma unroll
    for (int off = 32; off; off >>= 1) m = fmaxf(m, __shfl_xor(m, off));
    if (lane == 0)
      atomicMax(reinterpret_cast<unsigned*>(&out[b * 128 + o0 + j]), __float_as_uint(m));
  }
}

extern "C" void kernel_launch(void* const* d_in, const int* in_sizes, int n_in,
                              void* d_out, int out_size, void* d_ws, size_t ws_size,
                              hipStream_t stream) {
  const float* x    = (const float*)d_in[0];
  const int*   cls  = (const int*)d_in[1];
  const float* w_in = (const float*)d_in[2];
  const float* b_in = (const float*)d_in[3];
  const float* w1   = (const float*)d_in[4];
  const float* b1   = (const float*)d_in[5];
  const float* w2   = (const float*)d_in[6];
  const float* b2   = (const float*)d_in[7];
  const float* w3   = (const float*)d_in[8];
  const float* b3   = (const float*)d_in[9];
  const float* wo1  = (const float*)d_in[10];
  const float* bo1  = (const float*)d_in[11];
  const float* wo2  = (const float*)d_in[12];
  const float* bo2  = (const float*)d_in[13];
  float* out = (float*)d_out;

  char* ws = (char*)d_ws;
  float* f3g = (float*)ws;                                // 64 MB
  unsigned* part0 = (unsigned*)(ws + ((size_t)64 << 20)); // 3 x 8 KB (contiguous)
  unsigned* part1 = part0 + 8 * 2048;
  unsigned* part2 = part1 + 8 * 2048;
  float* poolc1 = (float*)(part2 + 8 * 2048);             // 8*1024
  float* poolc2 = poolc1 + 8 * 1024;
  float* poolco = poolc2 + 8 * 1024;                      // 8*2048

  hipMemsetAsync(d_out, 0, 1024 * sizeof(float), stream);
  hipMemsetAsync(part0, 0, 3 * 8 * 2048 * sizeof(unsigned), stream);

  k0_kern<<<NBLK, TPB, 0, stream>>>(x, cls, w_in, b_in, w1, b1, w2, b2, w3, b3, f3g, part0);
  pool_reduce_kern<64><<<8, 1024, 0, stream>>>(part0, w1 + (size_t)1 * 64 * 256, b1 + 64, poolc1);
  kmid_kern<<<NBLK, TPB, 0, stream>>>(f3g, poolc1, part1, cls, w1, w2, b2, w3, b3, 1);
  pool_reduce_kern<64><<<8, 1024, 0, stream>>>(part1, w1 + (size_t)2 * 64 * 256, b1 + 2 * 64, poolc2);
  kmid_kern<<<NBLK, TPB, 0, stream>>>(f3g, poolc2, part2, cls, w1, w2, b2, w3, b3, 2);
  pool_reduce_kern<128><<<8, 1024, 0, stream>>>(part2, wo1, bo1, poolco);
  k3_kern<<<NBLK, TPB, 0, stream>>>(f3g, poolco, cls, wo1, wo2, bo2, out);
}

// Round 4
// 834.567 us; speedup vs baseline: 2.1442x; 1.6327x over previous
//
#include <hip/hip_runtime.h>

// LapCluster fused fp32 pipeline for MI355X — round 4.
// r3 post-mortem: [ch][pt] LDS layout -> scalar ds_read_b32 x448/wave-tile, CPT=16
// -> 256 weight SGPRs/window (impossible) -> s_load/ds_read lgkmcnt serialization;
// 2 blocks/CU can't hide the barrier chain.
// r4: [pt][ch] LDS layout, padded row strides 132/68/28 (odd multiples of 4 floats
// -> all lane-row b128 accesses 2-way bank aliased = free). Lane = point reads its
// OWN row via ds_read_b128 (4x fewer LDS instrs); channel slices stay per-WAVE so
// weights stay uniform s_loads. TPB=1024 (16 waves/tile): CPT=4..8 -> <=64 weight
// SGPRs per unroll-2 window; LDS 58-62KB -> 2 blocks x 16 waves = 100% occupancy.
// f3g is POINT-MAJOR [pt][128] -> stage-in/out are coalesced float4.
// Pool trick: W*[f3,pool] = W[:,:128]*f3 + poolc[o][cluster] (per-batch tables);
// clusters always in [0,16). ReLU>=0 -> float-bit unsigned atomicMax exact.

#define TPB 1024
#define PT 64            // points per tile == wave size
#define NPB 16384
#define NPTS 131072
#define NC 16
#define TILES 2
#define NBLK 1024        // NPTS / (PT*TILES); 128 blocks/batch

#define FS 132           // F row stride (128ch + pad), 132*4B = 33*16B
#define AS 68            // A row stride (64ch + pad), 17*16B
#define XS 28            // x row stride (28ch), 7*16B

__device__ __forceinline__ float relu_(float v) { return fmaxf(v, 0.f); }

// acc[j] += sum_k W[j*WSTRIDE+k] * row[k]; row = lane's private LDS row (b128 reads),
// W wave-uniform -> s_loads. unroll 2 keeps weight SGPR window <= CPT*8.
template<int CPT, int WSTRIDE, int K>
__device__ __forceinline__ void accum_row(float* acc, const float* row,
                                          const float* __restrict__ W) {
#pragma unroll 2
  for (int k4 = 0; k4 < K / 4; ++k4) {
    float4 a = reinterpret_cast<const float4*>(row)[k4];
#pragma unroll
    for (int j = 0; j < CPT; ++j) {
      acc[j] = fmaf(W[j * WSTRIDE + k4 * 4 + 0], a.x, acc[j]);
      acc[j] = fmaf(W[j * WSTRIDE + k4 * 4 + 1], a.y, acc[j]);
      acc[j] = fmaf(W[j * WSTRIDE + k4 * 4 + 2], a.z, acc[j]);
      acc[j] = fmaf(W[j * WSTRIDE + k4 * 4 + 3], a.w, acc[j]);
    }
  }
}

__device__ __forceinline__ float4 relu4_(float a, float b, float c, float d) {
  return make_float4(relu_(a), relu_(b), relu_(c), relu_(d));
}

// ---- per-batch poolc table: poolc[o][cl] = bias[o] + W[o,128:]*pool
template<int O>
__global__ void __launch_bounds__(1024) pool_reduce_kern(
    const unsigned* __restrict__ part, const float* __restrict__ W,
    const float* __restrict__ bias, float* __restrict__ poolc_g) {
  __shared__ float pfL[2048];        // [k][cl] = k*16+cl
  __shared__ float Wl[O * 129];
  const int tid = threadIdx.x;
  const int b = blockIdx.x;
  for (int i = tid; i < 2048; i += 1024) pfL[i] = __uint_as_float(part[b * 2048 + i]);
  for (int i = tid; i < O * 128; i += 1024) {
    const int o = i >> 7, k = i & 127;
    Wl[o * 129 + k] = W[o * 256 + 128 + k];
  }
  __syncthreads();
  constexpr int SH = (O == 64) ? 6 : 7;
  for (int e = tid; e < O * 16; e += 1024) {
    const int o = e & (O - 1);
    const int cl = e >> SH;          // wave-uniform -> pfL broadcast
    float s = bias[o];
    const float* wr = &Wl[o * 129];
    const float* pr = &pfL[cl];
#pragma unroll 4
    for (int k = 0; k < 128; ++k) s = fmaf(wr[k], pr[k * 16], s);
    poolc_g[(size_t)b * (O * 16) + o * 16 + cl] = s;
  }
}

// ---- Stage 0: x -> f256 -> f64(w1[0]) -> f128(w2[0], pooled) -> f3_0(w3[0])
__global__ void __launch_bounds__(TPB, 8) k0_kern(
    const float* __restrict__ x, const int* __restrict__ cls,
    const float* __restrict__ w_in, const float* __restrict__ b_in,
    const float* __restrict__ w1, const float* __restrict__ b1,
    const float* __restrict__ w2, const float* __restrict__ b2,
    const float* __restrict__ w3, const float* __restrict__ b3,
    float* __restrict__ f3g, unsigned* __restrict__ part0) {
  __shared__ float F[PT * FS];       // 33792 B: f256 chunk -> f128
  __shared__ float AX[PT * AS];      // 17408 B: x rows (stride 28), later A64 (stride 68)
  __shared__ unsigned pool_s[128 * NC];  // 8192 B  (total 59392 B)
  const int tid = threadIdx.x;
  const int lane = tid & 63;
  const int w = __builtin_amdgcn_readfirstlane(tid >> 6);
  const int b = blockIdx.x >> 7;
  for (int i = tid; i < 128 * NC; i += TPB) pool_s[i] = 0u;

  float* xrow = &AX[lane * XS];
  float* frow = &F[lane * FS];
  float* arow = &AX[lane * AS];

  for (int t = 0; t < TILES; ++t) {
    const int tile0 = (blockIdx.x * TILES + t) * PT;
    {  // stage x: 64 pts x 28 f32 = 448 float4, contiguous
      const float4* src = reinterpret_cast<const float4*>(x + (size_t)tile0 * 28);
      if (tid < 448) reinterpret_cast<float4*>(AX)[tid] = src[tid];
    }
    const int cl0 = cls[tile0 + lane];
    __syncthreads();                 // B1: x staged (and pool_s inited, t=0)

    float acc64[4];
#pragma unroll
    for (int j = 0; j < 4; ++j) acc64[j] = b1[w * 4 + j];
#pragma unroll 1
    for (int c = 0; c < 2; ++c) {
      // f256 chunk c (128 ch): wave computes 8 ch of every... lane's own point
      const int o0 = c * 128 + w * 8;
      float acc[8];
#pragma unroll
      for (int j = 0; j < 8; ++j) acc[j] = b_in[o0 + j];
      accum_row<8, 28, 28>(acc, xrow, w_in + o0 * 28);
      *reinterpret_cast<float4*>(&frow[w * 8]) = relu4_(acc[0], acc[1], acc[2], acc[3]);
      *reinterpret_cast<float4*>(&frow[w * 8 + 4]) = relu4_(acc[4], acc[5], acc[6], acc[7]);
      __syncthreads();               // B2/B4: chunk staged
      accum_row<4, 256, 128>(acc64, frow, w1 + (w * 4) * 256 + c * 128);
      if (c == 1) {                  // A64 write: xbuf readers all done pre-B4
        *reinterpret_cast<float4*>(&arow[w * 4]) =
            relu4_(acc64[0], acc64[1], acc64[2], acc64[3]);
      }
      __syncthreads();               // B3/B5: chunk reads done (c=1: A staged)
    }
    {  // w2: 8 ch/wave from A64
      const int o0 = w * 8;
      float f128v[8];
#pragma unroll
      for (int j = 0; j < 8; ++j) f128v[j] = b2[o0 + j];
      accum_row<8, 64, 64>(f128v, arow, w2 + o0 * 64);
#pragma unroll
      for (int j = 0; j < 8; ++j) {
        f128v[j] = relu_(f128v[j]);
        atomicMax(&pool_s[(o0 + j) * NC + cl0], __float_as_uint(f128v[j]));
      }
      *reinterpret_cast<float4*>(&frow[o0]) = make_float4(f128v[0], f128v[1], f128v[2], f128v[3]);
      *reinterpret_cast<float4*>(&frow[o0 + 4]) = make_float4(f128v[4], f128v[5], f128v[6], f128v[7]);
    }
    __syncthreads();                 // B6: f128 staged
    {  // w3: 8 ch/wave -> f3g (point-major, coalesced-ish float4)
      const int o0 = w * 8;
      float w3a[8];
#pragma unroll
      for (int j = 0; j < 8; ++j) w3a[j] = b3[o0 + j];
      accum_row<8, 128, 128>(w3a, frow, w3 + o0 * 128);
      float4* dst = reinterpret_cast<float4*>(f3g + (size_t)(tile0 + lane) * 128 + o0);
      dst[0] = relu4_(w3a[0], w3a[1], w3a[2], w3a[3]);
      dst[1] = relu4_(w3a[4], w3a[5], w3a[6], w3a[7]);
    }
    __syncthreads();                 // B7: end of tile
  }
  for (int i = tid; i < 128 * NC; i += TPB)
    atomicMax(&part0[(size_t)b * 2048 + i], pool_s[i]);
}

// ---- Stages 1,2: f3_{S-1} -> f64(w1[S]+poolc) -> f128(w2[S], pooled) -> f3_S(w3[S])
__global__ void __launch_bounds__(TPB, 8) kmid_kern(
    float* __restrict__ f3g, const float* __restrict__ poolc_g,
    unsigned* __restrict__ part_cur, const int* __restrict__ cls,
    const float* __restrict__ w1, const float* __restrict__ w2,
    const float* __restrict__ b2, const float* __restrict__ w3,
    const float* __restrict__ b3, int S) {
  __shared__ float F[PT * FS];       // 33792
  __shared__ float A[PT * AS];       // 17408
  __shared__ float poolcL[64 * NC];  // 4096
  __shared__ unsigned pool_s[128 * NC];  // 8192 (total 63488 <= 64K)
  const int tid = threadIdx.x;
  const int lane = tid & 63;
  const int w = __builtin_amdgcn_readfirstlane(tid >> 6);
  const int b = blockIdx.x >> 7;
  const float* w1s = w1 + (size_t)S * 64 * 256;
  const float* w2s = w2 + (size_t)S * 128 * 64;
  const float* b2s = b2 + S * 128;
  const float* w3s = w3 + (size_t)S * 128 * 128;
  const float* b3s = b3 + S * 128;
  const int* clg = cls + (size_t)(S - 1) * NPTS;
  const int* clp = cls + (size_t)S * NPTS;
  for (int i = tid; i < 128 * NC; i += TPB) pool_s[i] = 0u;
  for (int i = tid; i < 64 * NC; i += TPB) poolcL[i] = poolc_g[(size_t)b * 1024 + i];

  float* frow = &F[lane * FS];
  float* arow = &A[lane * AS];

  for (int t = 0; t < TILES; ++t) {
    const int tile0 = (blockIdx.x * TILES + t) * PT;
    {  // stage f3 tile: point-major contiguous 32KB -> padded LDS rows
      const float4* src = reinterpret_cast<const float4*>(f3g + (size_t)tile0 * 128);
      for (int i = tid; i < 2048; i += TPB) {
        const int pt = i >> 5, c4 = i & 31;
        reinterpret_cast<float4*>(&F[pt * FS])[c4] = src[i];
      }
    }
    const int cg = clg[tile0 + lane];
    const int cp = clp[tile0 + lane];
    __syncthreads();                 // B1: staged
    {  // w1: 4 ch/wave, K=128, + poolc init
      float a4[4];
#pragma unroll
      for (int j = 0; j < 4; ++j) a4[j] = poolcL[(w * 4 + j) * NC + cg];
      accum_row<4, 256, 128>(a4, frow, w1s + (w * 4) * 256);
      *reinterpret_cast<float4*>(&arow[w * 4]) = relu4_(a4[0], a4[1], a4[2], a4[3]);
    }
    __syncthreads();                 // B2: A64 staged (F w1-readers done)
    {  // w2: 8 ch/wave + pool
      const int o0 = w * 8;
      float f128v[8];
#pragma unroll
      for (int j = 0; j < 8; ++j) f128v[j] = b2s[o0 + j];
      accum_row<8, 64, 64>(f128v, arow, w2s + o0 * 64);
#pragma unroll
      for (int j = 0; j < 8; ++j) {
        f128v[j] = relu_(f128v[j]);
        atomicMax(&pool_s[(o0 + j) * NC + cp], __float_as_uint(f128v[j]));
      }
      *reinterpret_cast<float4*>(&frow[o0]) = make_float4(f128v[0], f128v[1], f128v[2], f128v[3]);
      *reinterpret_cast<float4*>(&frow[o0 + 4]) = make_float4(f128v[4], f128v[5], f128v[6], f128v[7]);
    }
    __syncthreads();                 // B3: f128 staged
    {  // w3 -> f3g in place (this block's own tile rows)
      const int o0 = w * 8;
      float w3a[8];
#pragma unroll
      for (int j = 0; j < 8; ++j) w3a[j] = b3s[o0 + j];
      accum_row<8, 128, 128>(w3a, frow, w3s + o0 * 128);
      float4* dst = reinterpret_cast<float4*>(f3g + (size_t)(tile0 + lane) * 128 + o0);
      dst[0] = relu4_(w3a[0], w3a[1], w3a[2], w3a[3]);
      dst[1] = relu4_(w3a[4], w3a[5], w3a[6], w3a[7]);
    }
    __syncthreads();                 // B4: end of tile
  }
  for (int i = tid; i < 128 * NC; i += TPB)
    atomicMax(&part_cur[(size_t)b * 2048 + i], pool_s[i]);
}

// ---- Head: f3_2 -> o1(wo1+poolco, two 64-ch halves) -> o2(wo2) -> global max
__global__ void __launch_bounds__(TPB, 8) k3_kern(
    const float* __restrict__ f3g, const float* __restrict__ poolco_g,
    const int* __restrict__ cls,
    const float* __restrict__ wo1, const float* __restrict__ wo2,
    const float* __restrict__ bo2, float* __restrict__ out) {
  __shared__ float F[PT * FS];       // 33792
  __shared__ float A[PT * AS];       // 17408: o1 half
  __shared__ float poolcoL[128 * NC];  // 8192 (total 59392)
  const int tid = threadIdx.x;
  const int lane = tid & 63;
  const int w = __builtin_amdgcn_readfirstlane(tid >> 6);
  const int b = blockIdx.x >> 7;
  const int* clg = cls + (size_t)2 * NPTS;
  for (int i = tid; i < 128 * NC; i += TPB) poolcoL[i] = poolco_g[(size_t)b * 2048 + i];

  float* frow = &F[lane * FS];
  float* arow = &A[lane * AS];
  float omax[8];
#pragma unroll
  for (int j = 0; j < 8; ++j) omax[j] = 0.f;

  for (int t = 0; t < TILES; ++t) {
    const int tile0 = (blockIdx.x * TILES + t) * PT;
    {
      const float4* src = reinterpret_cast<const float4*>(f3g + (size_t)tile0 * 128);
      for (int i = tid; i < 2048; i += TPB) {
        const int pt = i >> 5, c4 = i & 31;
        reinterpret_cast<float4*>(&F[pt * FS])[c4] = src[i];
      }
    }
    const int cl = clg[tile0 + lane];
    __syncthreads();                 // B1: staged (t=0: poolcoL loaded)
    float o2acc[8];
#pragma unroll
    for (int j = 0; j < 8; ++j) o2acc[j] = bo2[w * 8 + j];
#pragma unroll 1
    for (int h = 0; h < 2; ++h) {
      // o1 half h: 4 ch/wave of this 64-ch half
      const int o0 = h * 64 + w * 4;
      float o1a[4];
#pragma unroll
      for (int j = 0; j < 4; ++j) o1a[j] = poolcoL[(o0 + j) * NC + cl];
      accum_row<4, 256, 128>(o1a, frow, wo1 + o0 * 256);
      *reinterpret_cast<float4*>(&arow[w * 4]) = relu4_(o1a[0], o1a[1], o1a[2], o1a[3]);
      __syncthreads();               // B2/B4: half staged (h=1: F o1-readers done)
      accum_row<8, 128, 64>(o2acc, arow, wo2 + (w * 8) * 128 + h * 64);
      if (h == 0) __syncthreads();   // B3: A reads done before h=1 rewrite
    }
#pragma unroll
    for (int j = 0; j < 8; ++j) omax[j] = fmaxf(omax[j], relu_(o2acc[j]));
    // no end barrier: next-tile F-stage is safe post-B4; A rewrite is post-next-B1.
  }
#pragma unroll
  for (int j = 0; j < 8; ++j) {
    float m = omax[j];
#pragma unroll
    for (int off = 32; off; off >>= 1) m = fmaxf(m, __shfl_xor(m, off));
    if (lane == 0)
      atomicMax(reinterpret_cast<unsigned*>(&out[b * 128 + w * 8 + j]), __float_as_uint(m));
  }
}

extern "C" void kernel_launch(void* const* d_in, const int* in_sizes, int n_in,
                              void* d_out, int out_size, void* d_ws, size_t ws_size,
                              hipStream_t stream) {
  const float* x    = (const float*)d_in[0];
  const int*   cls  = (const int*)d_in[1];
  const float* w_in = (const float*)d_in[2];
  const float* b_in = (const float*)d_in[3];
  const float* w1   = (const float*)d_in[4];
  const float* b1   = (const float*)d_in[5];
  const float* w2   = (const float*)d_in[6];
  const float* b2   = (const float*)d_in[7];
  const float* w3   = (const float*)d_in[8];
  const float* b3   = (const float*)d_in[9];
  const float* wo1  = (const float*)d_in[10];
  const float* bo1  = (const float*)d_in[11];
  const float* wo2  = (const float*)d_in[12];
  const float* bo2  = (const float*)d_in[13];
  float* out = (float*)d_out;

  char* ws = (char*)d_ws;
  float* f3g = (float*)ws;                                // 64 MB, point-major [pt][128]
  unsigned* part0 = (unsigned*)(ws + ((size_t)64 << 20)); // 3 x 8 KB
  unsigned* part1 = part0 + 8 * 2048;
  unsigned* part2 = part1 + 8 * 2048;
  float* poolc1 = (float*)(part2 + 8 * 2048);             // 8*1024
  float* poolc2 = poolc1 + 8 * 1024;
  float* poolco = poolc2 + 8 * 1024;                      // 8*2048

  hipMemsetAsync(d_out, 0, 1024 * sizeof(float), stream);
  hipMemsetAsync(part0, 0, 3 * 8 * 2048 * sizeof(unsigned), stream);

  k0_kern<<<NBLK, TPB, 0, stream>>>(x, cls, w_in, b_in, w1, b1, w2, b2, w3, b3, f3g, part0);
  pool_reduce_kern<64><<<8, 1024, 0, stream>>>(part0, w1 + (size_t)1 * 64 * 256, b1 + 64, poolc1);
  kmid_kern<<<NBLK, TPB, 0, stream>>>(f3g, poolc1, part1, cls, w1, w2, b2, w3, b3, 1);
  pool_reduce_kern<64><<<8, 1024, 0, stream>>>(part1, w1 + (size_t)2 * 64 * 256, b1 + 2 * 64, poolc2);
  kmid_kern<<<NBLK, TPB, 0, stream>>>(f3g, poolc2, part2, cls, w1, w2, b2, w3, b3, 2);
  pool_reduce_kern<128><<<8, 1024, 0, stream>>>(part2, wo1, bo1, poolco);
  k3_kern<<<NBLK, TPB, 0, stream>>>(f3g, poolco, cls, wo1, wo2, bo2, out);
}

// Round 6
// 822.983 us; speedup vs baseline: 2.1744x; 1.0141x over previous
//
#include <hip/hip_runtime.h>

// LapCluster fused fp32 pipeline for MI355X — round 6 (r5 + tail-guard fix).
// r5 bug: blocked accum_row had no tail guard; K=28 (w_in) read 1 float4 past
// the x row (stale LDS + OOB weights) -> absmax 1.98e-4. Fix: main blocked
// part NB=(K/4)/UNR*UNR + constexpr tail loop.
// Structure (r4/r5): [pt][ch] padded LDS rows (strides 132/68/28 floats ->
// b128 lane-row reads 2-way-bank-free); lane = point; channel slices per-wave
// -> weights stay uniform s_loads. f3g point-major [pt][128]. Register
// prefetch of next tile's stage-in issued right after B1; TILES=4, NBLK=512.
// Pool trick: W*[f3,pool] = W[:,:128]*f3 + poolc[o][cluster] per-batch tables;
// clusters in [0,16). ReLU>=0 -> float-bit unsigned atomicMax exact.

#define TPB 1024
#define PT 64            // points per tile == wave size
#define NPB 16384
#define NPTS 131072
#define NC 16
#define TILES 4
#define NBLK 512         // NPTS / (PT*TILES); 64 blocks/batch

#define FS 132           // F row stride (128ch + pad)
#define AS 68            // A row stride (64ch + pad)
#define XS 28            // x row stride

__device__ __forceinline__ float relu_(float v) { return fmaxf(v, 0.f); }

// acc[j] += sum_k W[j*WSTRIDE+k] * row[k]; row = lane-private LDS row (b128),
// W wave-uniform -> s_loads. Weight-SGPR window = CPT*UNR*4. Tail-safe.
template<int CPT, int WSTRIDE, int K, int UNR>
__device__ __forceinline__ void accum_row(float* acc, const float* row,
                                          const float* __restrict__ W) {
  const float4* rowv = reinterpret_cast<const float4*>(row);
  constexpr int NB = (K / 4) / UNR * UNR;   // blocked portion (multiple of UNR)
#pragma unroll 1
  for (int kb = 0; kb < NB; kb += UNR) {
#pragma unroll
    for (int u = 0; u < UNR; ++u) {
      float4 a = rowv[kb + u];
#pragma unroll
      for (int j = 0; j < CPT; ++j) {
        acc[j] = fmaf(W[j * WSTRIDE + (kb + u) * 4 + 0], a.x, acc[j]);
        acc[j] = fmaf(W[j * WSTRIDE + (kb + u) * 4 + 1], a.y, acc[j]);
        acc[j] = fmaf(W[j * WSTRIDE + (kb + u) * 4 + 2], a.z, acc[j]);
        acc[j] = fmaf(W[j * WSTRIDE + (kb + u) * 4 + 3], a.w, acc[j]);
      }
    }
  }
#pragma unroll
  for (int k4 = NB; k4 < K / 4; ++k4) {     // tail (K=28 case)
    float4 a = rowv[k4];
#pragma unroll
    for (int j = 0; j < CPT; ++j) {
      acc[j] = fmaf(W[j * WSTRIDE + k4 * 4 + 0], a.x, acc[j]);
      acc[j] = fmaf(W[j * WSTRIDE + k4 * 4 + 1], a.y, acc[j]);
      acc[j] = fmaf(W[j * WSTRIDE + k4 * 4 + 2], a.z, acc[j]);
      acc[j] = fmaf(W[j * WSTRIDE + k4 * 4 + 3], a.w, acc[j]);
    }
  }
}

__device__ __forceinline__ float4 relu4_(float a, float b, float c, float d) {
  return make_float4(relu_(a), relu_(b), relu_(c), relu_(d));
}

// ---- per-batch poolc table: poolc[o][cl] = bias[o] + W[o,128:]*pool
template<int O>
__global__ void __launch_bounds__(1024) pool_reduce_kern(
    const unsigned* __restrict__ part, const float* __restrict__ W,
    const float* __restrict__ bias, float* __restrict__ poolc_g) {
  __shared__ float pfL[2048];        // [k][cl] = k*16+cl
  __shared__ float Wl[O * 129];
  const int tid = threadIdx.x;
  const int b = blockIdx.x;
  for (int i = tid; i < 2048; i += 1024) pfL[i] = __uint_as_float(part[b * 2048 + i]);
  for (int i = tid; i < O * 128; i += 1024) {
    const int o = i >> 7, k = i & 127;
    Wl[o * 129 + k] = W[o * 256 + 128 + k];
  }
  __syncthreads();
  constexpr int SH = (O == 64) ? 6 : 7;
  for (int e = tid; e < O * 16; e += 1024) {
    const int o = e & (O - 1);
    const int cl = e >> SH;          // wave-uniform -> pfL broadcast
    float s = bias[o];
    const float* wr = &Wl[o * 129];
    const float* pr = &pfL[cl];
#pragma unroll 4
    for (int k = 0; k < 128; ++k) s = fmaf(wr[k], pr[k * 16], s);
    poolc_g[(size_t)b * (O * 16) + o * 16 + cl] = s;
  }
}

// ---- Stage 0: x -> f256 -> f64(w1[0]) -> f128(w2[0], pooled) -> f3_0(w3[0])
__global__ void __launch_bounds__(TPB, 8) k0_kern(
    const float* __restrict__ x, const int* __restrict__ cls,
    const float* __restrict__ w_in, const float* __restrict__ b_in,
    const float* __restrict__ w1, const float* __restrict__ b1,
    const float* __restrict__ w2, const float* __restrict__ b2,
    const float* __restrict__ w3, const float* __restrict__ b3,
    float* __restrict__ f3g, unsigned* __restrict__ part0) {
  __shared__ float F[PT * FS];       // 33792 B
  __shared__ float AX[PT * AS];      // 17408 B: x rows (28), later A64 (68)
  __shared__ unsigned pool_s[128 * NC];  // 8192 B (total 59392)
  const int tid = threadIdx.x;
  const int lane = tid & 63;
  const int w = __builtin_amdgcn_readfirstlane(tid >> 6);
  const int b = blockIdx.x >> 6;
  for (int i = tid; i < 128 * NC; i += TPB) pool_s[i] = 0u;

  float* xrow = &AX[lane * XS];
  float* frow = &F[lane * FS];
  float* arow = &AX[lane * AS];

  const int tb0 = blockIdx.x * TILES * PT;
  float4 xpre;
  if (tid < 448) xpre = reinterpret_cast<const float4*>(x + (size_t)tb0 * 28)[tid];
  int clN = cls[tb0 + lane];

  for (int t = 0; t < TILES; ++t) {
    const int tile0 = tb0 + t * PT;
    if (tid < 448) reinterpret_cast<float4*>(AX)[tid] = xpre;
    const int cl0 = clN;
    __syncthreads();                 // B1: x staged (t=0: pool_s inited)
    if (t + 1 < TILES) {             // prefetch next tile
      if (tid < 448)
        xpre = reinterpret_cast<const float4*>(x + (size_t)(tile0 + PT) * 28)[tid];
      clN = cls[tile0 + PT + lane];
    }

    float acc64[4];
#pragma unroll
    for (int j = 0; j < 4; ++j) acc64[j] = b1[w * 4 + j];
#pragma unroll 1
    for (int c = 0; c < 2; ++c) {    // f256 in two 128-ch chunks through F
      const int o0 = c * 128 + w * 8;
      float acc[8];
#pragma unroll
      for (int j = 0; j < 8; ++j) acc[j] = b_in[o0 + j];
      accum_row<8, 28, 28, 2>(acc, xrow, w_in + o0 * 28);
      *reinterpret_cast<float4*>(&frow[w * 8]) = relu4_(acc[0], acc[1], acc[2], acc[3]);
      *reinterpret_cast<float4*>(&frow[w * 8 + 4]) = relu4_(acc[4], acc[5], acc[6], acc[7]);
      __syncthreads();               // B2/B4: chunk staged (x reads done)
      accum_row<4, 256, 128, 4>(acc64, frow, w1 + (w * 4) * 256 + c * 128);
      if (c == 1) {                  // A64 write: post-B4, all x reads done
        *reinterpret_cast<float4*>(&arow[w * 4]) =
            relu4_(acc64[0], acc64[1], acc64[2], acc64[3]);
      }
      __syncthreads();               // B3/B5: chunk reads done (c=1: A staged)
    }
    {  // w2: 8 ch/wave from A64
      const int o0 = w * 8;
      float f128v[8];
#pragma unroll
      for (int j = 0; j < 8; ++j) f128v[j] = b2[o0 + j];
      accum_row<8, 64, 64, 2>(f128v, arow, w2 + o0 * 64);
#pragma unroll
      for (int j = 0; j < 8; ++j) {
        f128v[j] = relu_(f128v[j]);
        atomicMax(&pool_s[(o0 + j) * NC + cl0], __float_as_uint(f128v[j]));
      }
      *reinterpret_cast<float4*>(&frow[o0]) = make_float4(f128v[0], f128v[1], f128v[2], f128v[3]);
      *reinterpret_cast<float4*>(&frow[o0 + 4]) = make_float4(f128v[4], f128v[5], f128v[6], f128v[7]);
    }
    __syncthreads();                 // B6: f128 staged; AX (w2) readers done
    {  // w3: 8 ch/wave -> f3g point-major
      const int o0 = w * 8;
      float w3a[8];
#pragma unroll
      for (int j = 0; j < 8; ++j) w3a[j] = b3[o0 + j];
      accum_row<8, 128, 128, 2>(w3a, frow, w3 + o0 * 128);
      float4* dst = reinterpret_cast<float4*>(f3g + (size_t)(tile0 + lane) * 128 + o0);
      dst[0] = relu4_(w3a[0], w3a[1], w3a[2], w3a[3]);
      dst[1] = relu4_(w3a[4], w3a[5], w3a[6], w3a[7]);
    }
    // no end barrier: next x-write touches AX only (w2 readers fenced by B6);
    // F overwritten only after next B1 (every wave's w3 reads precede its B1).
  }
  for (int i = tid; i < 128 * NC; i += TPB)
    atomicMax(&part0[(size_t)b * 2048 + i], pool_s[i]);
}

// ---- Stages 1,2: f3_{S-1} -> f64(w1[S]+poolc) -> f128(w2[S], pooled) -> f3_S(w3[S])
__global__ void __launch_bounds__(TPB, 8) kmid_kern(
    float* __restrict__ f3g, const float* __restrict__ poolc_g,
    unsigned* __restrict__ part_cur, const int* __restrict__ cls,
    const float* __restrict__ w1, const float* __restrict__ w2,
    const float* __restrict__ b2, const float* __restrict__ w3,
    const float* __restrict__ b3, int S) {
  __shared__ float F[PT * FS];       // 33792
  __shared__ float A[PT * AS];       // 17408
  __shared__ float poolcL[64 * NC];  // 4096
  __shared__ unsigned pool_s[128 * NC];  // 8192 (total 63488)
  const int tid = threadIdx.x;
  const int lane = tid & 63;
  const int w = __builtin_amdgcn_readfirstlane(tid >> 6);
  const int b = blockIdx.x >> 6;
  const float* w1s = w1 + (size_t)S * 64 * 256;
  const float* w2s = w2 + (size_t)S * 128 * 64;
  const float* b2s = b2 + S * 128;
  const float* w3s = w3 + (size_t)S * 128 * 128;
  const float* b3s = b3 + S * 128;
  const int* clg = cls + (size_t)(S - 1) * NPTS;
  const int* clp = cls + (size_t)S * NPTS;
  for (int i = tid; i < 128 * NC; i += TPB) pool_s[i] = 0u;
  for (int i = tid; i < 64 * NC; i += TPB) poolcL[i] = poolc_g[(size_t)b * 1024 + i];

  float* frow = &F[lane * FS];
  float* arow = &A[lane * AS];
  const int pt0 = tid >> 5, c4 = tid & 31;      // stage mapping (2048 f4/tile)
  const int pt1 = (tid + 1024) >> 5;

  const int tb0 = blockIdx.x * TILES * PT;
  const float4* src4 = reinterpret_cast<const float4*>(f3g);
  float4 p0 = src4[(size_t)tb0 * 32 + tid];
  float4 p1 = src4[(size_t)tb0 * 32 + 1024 + tid];
  int cgN = clg[tb0 + lane], cpN = clp[tb0 + lane];

  for (int t = 0; t < TILES; ++t) {
    const int tile0 = tb0 + t * PT;
    reinterpret_cast<float4*>(&F[pt0 * FS])[c4] = p0;
    reinterpret_cast<float4*>(&F[pt1 * FS])[c4] = p1;
    const int cg = cgN, cp = cpN;
    __syncthreads();                 // B1: staged
    if (t + 1 < TILES) {
      p0 = src4[(size_t)(tile0 + PT) * 32 + tid];
      p1 = src4[(size_t)(tile0 + PT) * 32 + 1024 + tid];
      cgN = clg[tile0 + PT + lane];
      cpN = clp[tile0 + PT + lane];
    }
    {  // w1: 4 ch/wave, K=128, poolc init
      float a4[4];
#pragma unroll
      for (int j = 0; j < 4; ++j) a4[j] = poolcL[(w * 4 + j) * NC + cg];
      accum_row<4, 256, 128, 4>(a4, frow, w1s + (w * 4) * 256);
      *reinterpret_cast<float4*>(&arow[w * 4]) = relu4_(a4[0], a4[1], a4[2], a4[3]);
    }
    __syncthreads();                 // B2: A64 staged
    {  // w2: 8 ch/wave + pool
      const int o0 = w * 8;
      float f128v[8];
#pragma unroll
      for (int j = 0; j < 8; ++j) f128v[j] = b2s[o0 + j];
      accum_row<8, 64, 64, 2>(f128v, arow, w2s + o0 * 64);
#pragma unroll
      for (int j = 0; j < 8; ++j) {
        f128v[j] = relu_(f128v[j]);
        atomicMax(&pool_s[(o0 + j) * NC + cp], __float_as_uint(f128v[j]));
      }
      *reinterpret_cast<float4*>(&frow[o0]) = make_float4(f128v[0], f128v[1], f128v[2], f128v[3]);
      *reinterpret_cast<float4*>(&frow[o0 + 4]) = make_float4(f128v[4], f128v[5], f128v[6], f128v[7]);
    }
    __syncthreads();                 // B3: f128 staged
    {  // w3 -> f3g in place
      const int o0 = w * 8;
      float w3a[8];
#pragma unroll
      for (int j = 0; j < 8; ++j) w3a[j] = b3s[o0 + j];
      accum_row<8, 128, 128, 2>(w3a, frow, w3s + o0 * 128);
      float4* dst = reinterpret_cast<float4*>(f3g + (size_t)(tile0 + lane) * 128 + o0);
      dst[0] = relu4_(w3a[0], w3a[1], w3a[2], w3a[3]);
      dst[1] = relu4_(w3a[4], w3a[5], w3a[6], w3a[7]);
    }
    __syncthreads();                 // B4: w3 F-reads done before next stage
  }
  for (int i = tid; i < 128 * NC; i += TPB)
    atomicMax(&part_cur[(size_t)b * 2048 + i], pool_s[i]);
}

// ---- Head: f3_2 -> o1(wo1+poolco, two 64-ch halves) -> o2(wo2) -> global max
__global__ void __launch_bounds__(TPB, 8) k3_kern(
    const float* __restrict__ f3g, const float* __restrict__ poolco_g,
    const int* __restrict__ cls,
    const float* __restrict__ wo1, const float* __restrict__ wo2,
    const float* __restrict__ bo2, float* __restrict__ out) {
  __shared__ float F[PT * FS];       // 33792
  __shared__ float A[PT * AS];       // 17408
  __shared__ float poolcoL[128 * NC];  // 8192 (total 59392)
  const int tid = threadIdx.x;
  const int lane = tid & 63;
  const int w = __builtin_amdgcn_readfirstlane(tid >> 6);
  const int b = blockIdx.x >> 6;
  const int* clg = cls + (size_t)2 * NPTS;
  for (int i = tid; i < 128 * NC; i += TPB) poolcoL[i] = poolco_g[(size_t)b * 2048 + i];

  float* frow = &F[lane * FS];
  float* arow = &A[lane * AS];
  const int pt0 = tid >> 5, c4 = tid & 31;
  const int pt1 = (tid + 1024) >> 5;
  float omax[8];
#pragma unroll
  for (int j = 0; j < 8; ++j) omax[j] = 0.f;

  const int tb0 = blockIdx.x * TILES * PT;
  const float4* src4 = reinterpret_cast<const float4*>(f3g);
  float4 p0 = src4[(size_t)tb0 * 32 + tid];
  float4 p1 = src4[(size_t)tb0 * 32 + 1024 + tid];
  int clN = clg[tb0 + lane];

  for (int t = 0; t < TILES; ++t) {
    const int tile0 = tb0 + t * PT;
    reinterpret_cast<float4*>(&F[pt0 * FS])[c4] = p0;
    reinterpret_cast<float4*>(&F[pt1 * FS])[c4] = p1;
    const int cl = clN;
    __syncthreads();                 // B1 (t=0: poolcoL loaded)
    if (t + 1 < TILES) {
      p0 = src4[(size_t)(tile0 + PT) * 32 + tid];
      p1 = src4[(size_t)(tile0 + PT) * 32 + 1024 + tid];
      clN = clg[tile0 + PT + lane];
    }
    float o2acc[8];
#pragma unroll
    for (int j = 0; j < 8; ++j) o2acc[j] = bo2[w * 8 + j];
#pragma unroll 1
    for (int h = 0; h < 2; ++h) {
      const int o0 = h * 64 + w * 4;
      float o1a[4];
#pragma unroll
      for (int j = 0; j < 4; ++j) o1a[j] = poolcoL[(o0 + j) * NC + cl];
      accum_row<4, 256, 128, 4>(o1a, frow, wo1 + o0 * 256);
      *reinterpret_cast<float4*>(&arow[w * 4]) = relu4_(o1a[0], o1a[1], o1a[2], o1a[3]);
      __syncthreads();               // B2/B4: half staged
      accum_row<8, 128, 64, 2>(o2acc, arow, wo2 + (w * 8) * 128 + h * 64);
      if (h == 0) __syncthreads();   // B3: A reads done before h=1 rewrite
    }
#pragma unroll
    for (int j = 0; j < 8; ++j) omax[j] = fmaxf(omax[j], relu_(o2acc[j]));
    __syncthreads();                 // end: F o1-readers + A o2-readers done
  }
#pragma unroll
  for (int j = 0; j < 8; ++j) {
    float m = omax[j];
#pragma unroll
    for (int off = 32; off; off >>= 1) m = fmaxf(m, __shfl_xor(m, off));
    if (lane == 0)
      atomicMax(reinterpret_cast<unsigned*>(&out[b * 128 + w * 8 + j]), __float_as_uint(m));
  }
}

extern "C" void kernel_launch(void* const* d_in, const int* in_sizes, int n_in,
                              void* d_out, int out_size, void* d_ws, size_t ws_size,
                              hipStream_t stream) {
  const float* x    = (const float*)d_in[0];
  const int*   cls  = (const int*)d_in[1];
  const float* w_in = (const float*)d_in[2];
  const float* b_in = (const float*)d_in[3];
  const float* w1   = (const float*)d_in[4];
  const float* b1   = (const float*)d_in[5];
  const float* w2   = (const float*)d_in[6];
  const float* b2   = (const float*)d_in[7];
  const float* w3   = (const float*)d_in[8];
  const float* b3   = (const float*)d_in[9];
  const float* wo1  = (const float*)d_in[10];
  const float* bo1  = (const float*)d_in[11];
  const float* wo2  = (const float*)d_in[12];
  const float* bo2  = (const float*)d_in[13];
  float* out = (float*)d_out;

  char* ws = (char*)d_ws;
  float* f3g = (float*)ws;                                // 64 MB, point-major [pt][128]
  unsigned* part0 = (unsigned*)(ws + ((size_t)64 << 20)); // 3 x 8 KB
  unsigned* part1 = part0 + 8 * 2048;
  unsigned* part2 = part1 + 8 * 2048;
  float* poolc1 = (float*)(part2 + 8 * 2048);             // 8*1024
  float* poolc2 = poolc1 + 8 * 1024;
  float* poolco = poolc2 + 8 * 1024;                      // 8*2048

  hipMemsetAsync(d_out, 0, 1024 * sizeof(float), stream);
  hipMemsetAsync(part0, 0, 3 * 8 * 2048 * sizeof(unsigned), stream);

  k0_kern<<<NBLK, TPB, 0, stream>>>(x, cls, w_in, b_in, w1, b1, w2, b2, w3, b3, f3g, part0);
  pool_reduce_kern<64><<<8, 1024, 0, stream>>>(part0, w1 + (size_t)1 * 64 * 256, b1 + 64, poolc1);
  kmid_kern<<<NBLK, TPB, 0, stream>>>(f3g, poolc1, part1, cls, w1, w2, b2, w3, b3, 1);
  pool_reduce_kern<64><<<8, 1024, 0, stream>>>(part1, w1 + (size_t)2 * 64 * 256, b1 + 2 * 64, poolc2);
  kmid_kern<<<NBLK, TPB, 0, stream>>>(f3g, poolc2, part2, cls, w1, w2, b2, w3, b3, 2);
  pool_reduce_kern<128><<<8, 1024, 0, stream>>>(part2, wo1, bo1, poolco);
  k3_kern<<<NBLK, TPB, 0, stream>>>(f3g, poolco, cls, wo1, wo2, bo2, out);
}